// Round 15
// baseline (184.334 us; speedup 1.0000x reference)
//
#include <hip/hip_runtime.h>
#include <hip/hip_bf16.h>

// MMD loss via bf16 MFMA Gram matrix — R15: register-resident B-panel + 4
// column-major tiles per 1-wave block + cross-tile pipelining + exp-chain.
// Five K-loop structures (R3..R14) plateau at 45-53us with VALUBusy~33,
// MfmaUtil~13: per-tile load-inst count (64) + serial 2.6k-cyc epilogue is the
// remaining consistent theory. This round: 32 A-loads/tile (B in 128 VGPRs,
// reloaded only on column change), next tile's chunk-0 issued BEFORE the
// epilogue (epilogue hides its latency), e(s=10)=e(s=100)^10 chain (exact,
// guarded).
//
// Zc layout (R7): Zc[ck][row][32], stored quad = q ^ ((row>>1)&3); each mfma
// fragment = one contiguous coalesced 1KB block.
// Lessons: R4 no fences in hot kernels; R5 spill = death (launch_bounds(64,2)
// caps 256 VGPR > ~190 need); R6 no scattered loads; R13 coop/grid.sync dead;
// R14 huge tiny-block grids add CP ramp (2064 blocks here).
//
// ws: [0,4MiB) bf16 Zc; float norms_part[4][8192]; float norms[8192];
//     float partials[2064].

#define NSIG 5
#define CKS  262144                  // chunk stride in ushorts: 8192 rows * 32
#define NWT  8256                    // 128*129/2 wave-tiles
#define NGB  2064                    // gemm blocks, 4 tiles each (exact)

typedef __attribute__((ext_vector_type(8))) short short8;
typedef __attribute__((ext_vector_type(4))) float floatx4;

// ---- prep (verified R13/R14): job = s(1)|b(2)|cgh(2)|pq(2), 128 blocks ----
__global__ __launch_bounds__(256) void prep_kernel(const float* __restrict__ x,
                                                   const float* __restrict__ y,
                                                   ushort* __restrict__ Zc,
                                                   float* __restrict__ norms_part) {
    __shared__ ushort tile[32 * 256];
    const int job = blockIdx.x, t = threadIdx.x;
    const int s   = job >> 6;
    const int b   = (job >> 4) & 3;
    const int cgh = (job >> 2) & 3;
    const int pq  = job & 3;
    const float* src = s ? y : x;
    const int p0 = pq << 8;
    const int n0 = (s << 12) + (b << 10) + p0;
    const int row = n0 + t;
    const int sw = (row >> 1) & 3;
    float ns = 0.f;

    for (int h = 0; h < 2; ++h) {
        const int cgi = (cgh << 1) + h;
        __syncthreads();
#pragma unroll
        for (int it = 0; it < 8; ++it) {
            const int g = (it << 8) + t;
            const int cl = g >> 6;
            const int pf = (g & 63) << 2;
            const float4 v = *(const float4*)(src +
                ((size_t)((b << 8) + (cgi << 5) + cl) << 10) + p0 + pf);
            const __hip_bfloat16 h0 = __float2bfloat16(v.x);
            const __hip_bfloat16 h1 = __float2bfloat16(v.y);
            const __hip_bfloat16 h2 = __float2bfloat16(v.z);
            const __hip_bfloat16 h3 = __float2bfloat16(v.w);
            const uint u0 = (uint)(*(const ushort*)&h0) | ((uint)(*(const ushort*)&h1) << 16);
            const uint u1 = (uint)(*(const ushort*)&h2) | ((uint)(*(const ushort*)&h3) << 16);
            *(uint2*)(&tile[(cl << 8) + pf]) = make_uint2(u0, u1);
        }
        __syncthreads();
        uint pk[16];
#pragma unroll
        for (int c = 0; c < 32; ++c) {
            const ushort uv = tile[(c << 8) + t];
            const float f = __bfloat162float(*(const __hip_bfloat16*)&uv);
            ns = fmaf(f, f, ns);
            if ((c & 1) == 0) pk[c >> 1] = (uint)uv;
            else              pk[c >> 1] |= ((uint)uv) << 16;
        }
        ushort* dst = Zc + (size_t)cgi * CKS + ((size_t)row << 5);
#pragma unroll
        for (int qq = 0; qq < 4; ++qq) {
            const int sq = qq ^ sw;
            *(uint4*)(dst + (sq << 3)) = make_uint4(pk[4*qq], pk[4*qq+1], pk[4*qq+2], pk[4*qq+3]);
        }
    }
    norms_part[(cgh << 13) + row] = ns;
}

__global__ __launch_bounds__(256) void nred_kernel(const float* __restrict__ norms_part,
                                                   float* __restrict__ norms) {
    const int row = (blockIdx.x << 8) + threadIdx.x;
    float s = 0.f;
#pragma unroll
    for (int g = 0; g < 4; ++g) s += norms_part[(g << 13) + row];
    norms[row] = s;
}

// ---- gemm: 1 wave/block, 4 column-major tiles, B-panel in registers ----
__global__ __launch_bounds__(64, 2) void gemm_epi(const ushort* __restrict__ Zc,
                                                  const float* __restrict__ norms,
                                                  const float* __restrict__ sigmas,
                                                  float* __restrict__ partials) {
    const int l = threadIdx.x;
    const int m = l & 15, q = l >> 4;
    const int lin0 = blockIdx.x << 2;

    // decode first tile (column-major: column tj holds ti = 0..tj)
    int tj = (int)((sqrtf(8.f * (float)lin0 + 1.f) - 1.f) * 0.5f);
    tj = tj < 0 ? 0 : (tj > 127 ? 127 : tj);
    while (((tj + 1) * (tj + 2)) / 2 <= lin0) ++tj;
    while ((tj * (tj + 1)) / 2 > lin0) --tj;
    int ti = lin0 - (tj * (tj + 1)) / 2;

    float c2[NSIG];
#pragma unroll
    for (int k = 0; k < NSIG; ++k) c2[k] = (-0.5f / sigmas[k]) * 1.44269504f;
    const bool chainOK = fabsf(c2[3] - 10.f * c2[4]) <= 1e-5f * fabsf(c2[3]);

    // B-panel registers for column tj (reloaded on column change)
    short8 bb[8][4];
#pragma unroll
    for (int f = 0; f < 4; ++f) {
        const int rb = (tj << 6) + (f << 4) + m;
        const int ob = (rb << 5) + ((q ^ ((rb >> 1) & 3)) << 3);
#pragma unroll
        for (int ck = 0; ck < 8; ++ck)
            bb[ck][f] = *(const short8*)(Zc + (size_t)ck * CKS + ob);
    }

    // A chunk-0 of first tile
    int offA[4];
#pragma unroll
    for (int f = 0; f < 4; ++f) {
        const int ra = (ti << 6) + (f << 4) + m;
        offA[f] = (ra << 5) + ((q ^ ((ra >> 1) & 3)) << 3);
    }
    short8 curA[4], nxtA[4];
#pragma unroll
    for (int f = 0; f < 4; ++f) curA[f] = *(const short8*)(Zc + offA[f]);

    float ltot = 0.f;

    for (int u = 0; u < 4; ++u) {
        const int i0 = ti << 6, j0 = tj << 6;
        const bool diag = (ti == tj);
        const float sgn2 = ((ti < 64) == (tj < 64)) ? 2.f : -2.f;

        floatx4 accf[4][4];
#pragma unroll
        for (int fi = 0; fi < 4; ++fi)
#pragma unroll
            for (int fj = 0; fj < 4; ++fj) accf[fi][fj] = (floatx4){0.f, 0.f, 0.f, 0.f};

        // K-loop: only A streams; B is register-resident
#pragma unroll
        for (int ck = 0; ck < 8; ++ck) {
            if (ck < 7) {
                const size_t ko = (size_t)(ck + 1) * CKS;
#pragma unroll
                for (int f = 0; f < 4; ++f)
                    nxtA[f] = *(const short8*)(Zc + ko + offA[f]);
            }
#pragma unroll
            for (int fi = 0; fi < 4; ++fi)
#pragma unroll
                for (int fj = 0; fj < 4; ++fj)
                    accf[fi][fj] = __builtin_amdgcn_mfma_f32_16x16x32_bf16(curA[fi], bb[ck][fj], accf[fi][fj], 0, 0, 0);
            if (ck < 7) {
#pragma unroll
                for (int f = 0; f < 4; ++f) curA[f] = nxtA[f];
            }
        }

        // advance + issue next tile's loads BEFORE the epilogue (latency hidden)
        if (u < 3) {
            int nti = ti + 1, ntj = tj;
            const bool newcol = (nti > ntj);
            if (newcol) { nti = 0; ++ntj; }
#pragma unroll
            for (int f = 0; f < 4; ++f) {
                const int ra = (nti << 6) + (f << 4) + m;
                offA[f] = (ra << 5) + ((q ^ ((ra >> 1) & 3)) << 3);
            }
            if (newcol) {
#pragma unroll
                for (int f = 0; f < 4; ++f) {
                    const int rb = (ntj << 6) + (f << 4) + m;
                    const int ob = (rb << 5) + ((q ^ ((rb >> 1) & 3)) << 3);
#pragma unroll
                    for (int ck = 0; ck < 8; ++ck)
                        bb[ck][f] = *(const short8*)(Zc + (size_t)ck * CKS + ob);
                }
            }
#pragma unroll
            for (int f = 0; f < 4; ++f) curA[f] = *(const short8*)(Zc + offA[f]);
            // epilogue below uses current-tile i0/j0/diag/sgn2; update indices after
            ti = nti; tj = ntj;
        }

        // ---- epilogue ----
#pragma unroll
        for (int fi = 0; fi < 4; ++fi) {
            const floatx4 ni4 = *(const floatx4*)(norms + i0 + (fi << 4) + (q << 2));
#pragma unroll
            for (int fj = 0; fj < 4; ++fj) {
                const float njs = norms[j0 + (fj << 4) + m];
#pragma unroll
                for (int v = 0; v < 4; ++v) {
                    float d = fmaf(-2.f, accf[fi][fj][v], ni4[v] + njs);
                    d = fmaxf(d, 0.f);
                    if (diag) {
                        const int dif = ((fi - fj) << 4) + ((q << 2) + v) - m;
                        d = (dif < 0) ? d : 3.0e9f;   // strictly-upper only
                    }
                    accf[fi][fj][v] = d;
                }
            }
        }

        float dmin = accf[0][0][0];
#pragma unroll
        for (int fi = 0; fi < 4; ++fi)
#pragma unroll
            for (int fj = 0; fj < 4; ++fj)
#pragma unroll
                for (int v = 0; v < 4; ++v) dmin = fminf(dmin, accf[fi][fj][v]);
#pragma unroll
        for (int off = 1; off < 64; off <<= 1) dmin = fminf(dmin, __shfl_xor(dmin, off, 64));

        bool skip[NSIG];
#pragma unroll
        for (int k = 0; k < NSIG; ++k) skip[k] = (c2[k] * dmin < -126.f);

        float tsum = 0.f;
#pragma unroll
        for (int fi = 0; fi < 4; ++fi)
#pragma unroll
            for (int fj = 0; fj < 4; ++fj)
#pragma unroll
                for (int v = 0; v < 4; ++v) {
                    const float d = accf[fi][fj][v];
#pragma unroll
                    for (int k = 0; k < 3; ++k)
                        if (!skip[k]) tsum += __builtin_amdgcn_exp2f(c2[k] * d);
                    if (!skip[4]) {
                        const float e4 = __builtin_amdgcn_exp2f(c2[4] * d);
                        tsum += e4;
                        if (!skip[3]) {
                            if (chainOK) {
                                const float e2 = e4 * e4;
                                const float e5 = e2 * e2 * e4;   // e4^5
                                tsum += e5 * e5;                 // e4^10 = exp2(10*c4*d)
                            } else {
                                tsum += __builtin_amdgcn_exp2f(c2[3] * d);
                            }
                        }
                    } else if (!skip[3]) {
                        tsum += __builtin_amdgcn_exp2f(c2[3] * d);
                    }
                }
        ltot = fmaf(sgn2, tsum, ltot);
    }

#pragma unroll
    for (int off = 32; off > 0; off >>= 1) ltot += __shfl_down(ltot, off, 64);
    if (l == 0) partials[blockIdx.x] = ltot;
}

__global__ __launch_bounds__(256) void fin_kernel(const float* __restrict__ partials,
                                                  float* __restrict__ out) {
    __shared__ double sh[256];
    const int t = threadIdx.x;
    double s = 0.0;
    for (int i = t; i < NGB; i += 256) s += (double)partials[i];
    sh[t] = s;
    __syncthreads();
    for (int st = 128; st > 0; st >>= 1) {
        if (t < st) sh[t] += sh[t + st];
        __syncthreads();
    }
    if (t == 0) out[0] = (float)((sh[0] + 8192.0 * NSIG) * (1.0 / (4096.0 * 4096.0)));
}

extern "C" void kernel_launch(void* const* d_in, const int* in_sizes, int n_in,
                              void* d_out, int out_size, void* d_ws, size_t ws_size,
                              hipStream_t stream) {
    const float* x   = (const float*)d_in[0];
    const float* y   = (const float*)d_in[1];
    const float* sig = (const float*)d_in[2];

    ushort* Zc        = (ushort*)d_ws;                                          // 4 MiB
    float* norms_part = (float*)((char*)d_ws + (size_t)8192 * 256 * 2);         // 128 KiB
    float* norms      = (float*)((char*)norms_part + 4 * 8192 * sizeof(float)); // 32 KiB
    float* partials   = (float*)((char*)norms + 8192 * sizeof(float));          // 8.3 KiB
    float* out        = (float*)d_out;

    prep_kernel<<<128, 256, 0, stream>>>(x, y, Zc, norms_part);
    nred_kernel<<<32, 256, 0, stream>>>(norms_part, norms);
    gemm_epi<<<NGB, 64, 0, stream>>>(Zc, norms, sig, partials);
    fin_kernel<<<1, 256, 0, stream>>>(partials, out);
}